// Round 1
// 162.129 us; speedup vs baseline: 1.0075x; 1.0075x over previous
//
#include <hip/hip_runtime.h>

#define THREADS 256

typedef __attribute__((ext_vector_type(8))) short bf16x8;
typedef __attribute__((ext_vector_type(4))) float f32x4;

// fp32 -> bf16 with round-to-nearest-even (matches HW convert)
__device__ inline unsigned short f2bf(float f) {
    union { float f; unsigned int u; } v; v.f = f;
    unsigned int r = v.u + 0x7fffu + ((v.u >> 16) & 1u);
    return (unsigned short)(r >> 16);
}

// LDS-only barrier: makes LDS writes visible without draining vmcnt
// (y-stores stay in flight across it). Guide-verified pattern (8-phase
// template); empty asm fences stop compiler reordering of mem ops.
__device__ inline void lds_barrier() {
    asm volatile("s_waitcnt lgkmcnt(0)" ::: "memory");
    __builtin_amdgcn_s_barrier();
    asm volatile("" ::: "memory");
}

// ---------------------------------------------------------------------------
// Kernel A: in-side contraction  x[N,4096] -> u3b[N,512] (bf16)
//   (UNCHANGED from verified baseline — any perf delta isolates to fusion)
// ---------------------------------------------------------------------------
__global__ __launch_bounds__(THREADS) void k_in_contract(
    const float* __restrict__ x,
    const float* __restrict__ f3, const float* __restrict__ f4,
    const float* __restrict__ f5,
    unsigned short* __restrict__ u3b, int N)
{
    const int n = blockIdx.x;
    const int t = threadIdx.x;

    __shared__ float fs[256];        // f3 [0..128) | f4 [128..256)
    __shared__ float u1s[256 * 9];   // [de][n6], pad 9 -> 2-way max
    __shared__ float u2s[128 * 9];   // [d*8+m][n6], pad 9

    if (t < 128) { fs[t] = f3[t]; fs[128 + t] = f4[t]; }

    float xv[16];
    {
        const float4* xr = (const float4*)(x + (size_t)n * 4096 + t * 16);
        float4 a0 = xr[0], a1 = xr[1], a2 = xr[2], a3 = xr[3];
        xv[0]=a0.x; xv[1]=a0.y; xv[2]=a0.z; xv[3]=a0.w;
        xv[4]=a1.x; xv[5]=a1.y; xv[6]=a1.z; xv[7]=a1.w;
        xv[8]=a2.x; xv[9]=a2.y; xv[10]=a2.z; xv[11]=a2.w;
        xv[12]=a3.x; xv[13]=a3.y; xv[14]=a3.z; xv[15]=a3.w;
    }

    float acc8[8];
    #pragma unroll
    for (int q = 0; q < 8; ++q) acc8[q] = 0.f;
    #pragma unroll
    for (int f = 0; f < 16; ++f) {
        const float xf = xv[f];
        #pragma unroll
        for (int n6 = 0; n6 < 8; ++n6)
            acc8[n6] = fmaf(xf, f5[f*8 + n6], acc8[n6]);
    }
    __syncthreads();
    #pragma unroll
    for (int n6 = 0; n6 < 8; ++n6) u1s[t*9 + n6] = acc8[n6];
    __syncthreads();

    {
        const int d = t >> 4, m = (t >> 1) & 7, h = t & 1;
        float fr[16];
        #pragma unroll
        for (int e = 0; e < 16; ++e) fr[e] = fs[128 + e*8 + m];
        float a4[4] = {0.f, 0.f, 0.f, 0.f};
        #pragma unroll
        for (int e = 0; e < 16; ++e) {
            const int base = (d*16 + e)*9 + h*4;
            #pragma unroll
            for (int q = 0; q < 4; ++q)
                a4[q] = fmaf(u1s[base + q], fr[e], a4[q]);
        }
        #pragma unroll
        for (int q = 0; q < 4; ++q) u2s[(d*8 + m)*9 + h*4 + q] = a4[q];
    }
    __syncthreads();

    {
        const int l = t >> 5, m = (t >> 2) & 7, h = t & 3;
        float fr[16];
        #pragma unroll
        for (int d = 0; d < 16; ++d) fr[d] = fs[d*8 + l];
        float a2[2] = {0.f, 0.f};
        #pragma unroll
        for (int d = 0; d < 16; ++d) {
            const int base = (d*8 + m)*9 + h*2;
            a2[0] = fmaf(u2s[base],     fr[d], a2[0]);
            a2[1] = fmaf(u2s[base + 1], fr[d], a2[1]);
        }
        unsigned int pk = (unsigned int)f2bf(a2[0]) |
                          ((unsigned int)f2bf(a2[1]) << 16);
        ((unsigned int*)u3b)[(size_t)n * 256 + t] = pk;
    }
}

// ---------------------------------------------------------------------------
// core fp32 [512,512] -> bf16. (UNCHANGED)
// ---------------------------------------------------------------------------
__global__ __launch_bounds__(THREADS) void k_convert_core(
    const float* __restrict__ core, unsigned short* __restrict__ coreb)
{
    const int i = blockIdx.x * THREADS + threadIdx.x;
    float4 c = ((const float4*)core)[i];
    ushort4 o;
    o.x = f2bf(c.x); o.y = f2bf(c.y); o.z = f2bf(c.z); o.w = f2bf(c.w);
    ((ushort4*)coreb)[i] = o;
}

// ---------------------------------------------------------------------------
// Kernel B+C fused: GEMM (MFMA) + out-side expansion, v stays in LDS.
//   Block = 512 thr (8 waves), owns 16 batch rows (one MFMA M-tile).
//   Grid = N/16 = 256 blocks (1 block/CU, 2 waves/SIMD).
//
//   Phase 1: v[16,512] = u3[16,512] * coreb[512,512]^T  (16x16x32 bf16 MFMA)
//     wave w owns p-cols [w*64, w*64+64): 4 tiles x 16 k-steps.
//     A-frag: lane holds row n0+lr, k=lq*8+j   (verified layout, m89/m91)
//     C/D:    col = lane&15, row = (lane>>4)*4 + reg
//   Phase 2: 2 rows/iter (rp = t>>8), 8 iters. w2 accumulator kept in
//     REGISTERS (w2s round-trip in the old kernel was same-thread — dead).
// ---------------------------------------------------------------------------
#define GE_THREADS 512
#define VSTRIDE 516   // 516%32=4 -> breaks same-bank between lq row-groups

__global__ __launch_bounds__(GE_THREADS) void k_gemm_expand(
    const unsigned short* __restrict__ u3b,
    const unsigned short* __restrict__ coreb,
    const float* __restrict__ f0, const float* __restrict__ f1,
    const float* __restrict__ f2, const float* __restrict__ bias,
    float* __restrict__ y, int N)
{
    const int t  = threadIdx.x;
    const int n0 = blockIdx.x * 16;
    const int tt = t & 255;
    const int rp = t >> 8;           // row-parity: waves 0-3 vs 4-7

    __shared__ float fs[256];            // f0 [0..128) | f1 [128..256)
    __shared__ float v_lds[16 * VSTRIDE];
    __shared__ float w1s[2 * 128 * 9];   // per-rp scratch, pad 9

    if (t < 128) fs[t] = f0[t];
    else if (t < 256) fs[t] = f1[t - 128];

    // bias for this thread's 16 output cols (same every row -> hoist)
    float4 b4[4];
    {
        const float4* bp = (const float4*)(bias + tt * 16);
        b4[0] = bp[0]; b4[1] = bp[1]; b4[2] = bp[2]; b4[3] = bp[3];
    }

    // ---- Phase 1: MFMA GEMM into LDS --------------------------------------
    {
        const int lane = t & 63;
        const int w  = t >> 6;       // 0..7
        const int lr = lane & 15;
        const int lq = lane >> 4;

        const unsigned short* ap = u3b + (size_t)(n0 + lr) * 512 + lq * 8;
        bf16x8 a[16];
        #pragma unroll
        for (int kt = 0; kt < 16; ++kt)
            a[kt] = *(const bf16x8*)(ap + kt * 32);

        const unsigned short* bp0 = coreb + (size_t)(w * 64 + lr) * 512 + lq * 8;
        f32x4 acc[4] = {{0.f,0.f,0.f,0.f},{0.f,0.f,0.f,0.f},
                        {0.f,0.f,0.f,0.f},{0.f,0.f,0.f,0.f}};
        #pragma unroll
        for (int kt = 0; kt < 16; ++kt) {
            #pragma unroll
            for (int j = 0; j < 4; ++j) {
                bf16x8 b = *(const bf16x8*)(bp0 + (size_t)j * 16 * 512 + kt * 32);
                acc[j] = __builtin_amdgcn_mfma_f32_16x16x32_bf16(a[kt], b, acc[j], 0, 0, 0);
            }
        }
        #pragma unroll
        for (int j = 0; j < 4; ++j) {
            #pragma unroll
            for (int r = 0; r < 4; ++r)
                v_lds[(lq*4 + r) * VSTRIDE + w*64 + j*16 + lr] = acc[j][r];
        }
    }
    __syncthreads();

    // ---- Phase 2: out-side expansion, 2 rows per iteration ----------------
    const int a1 = tt >> 4, j1 = (tt >> 1) & 7, h1 = tt & 1;  // w1 role
    const int b2 = tt & 15;                                   // w2/y role (a2==a1)
    float fr1[8], fr2[8];
    #pragma unroll
    for (int i = 0; i < 8; ++i) fr1[i] = fs[a1*8 + i];
    #pragma unroll
    for (int j = 0; j < 8; ++j) fr2[j] = fs[128 + b2*8 + j];

    float* w1p = w1s + rp * (128 * 9);

    #pragma unroll 1
    for (int it = 0; it < 8; ++it) {
        const int row = it * 2 + rp;
        const float* vrow = v_lds + row * VSTRIDE;

        // w1[a,j,k] = sum_i v[row, i*64+j*8+k] * f0[a,i]
        {
            float a4[4] = {0.f, 0.f, 0.f, 0.f};
            #pragma unroll
            for (int i = 0; i < 8; ++i) {
                const int base = i*64 + j1*8 + h1*4;
                const float fi = fr1[i];
                #pragma unroll
                for (int q = 0; q < 4; ++q)
                    a4[q] = fmaf(vrow[base + q], fi, a4[q]);
            }
            #pragma unroll
            for (int q = 0; q < 4; ++q)
                w1p[(a1*8 + j1)*9 + h1*4 + q] = a4[q];
        }
        lds_barrier();

        // w2 in regs (same-thread identity), then y = w2 . f2^T + bias
        {
            float a8[8] = {0.f,0.f,0.f,0.f,0.f,0.f,0.f,0.f};
            #pragma unroll
            for (int j = 0; j < 8; ++j) {
                const int base = (a1*8 + j)*9;
                const float fj = fr2[j];
                #pragma unroll
                for (int k = 0; k < 8; ++k)
                    a8[k] = fmaf(w1p[base + k], fj, a8[k]);
            }
            float yv[16];
            #pragma unroll
            for (int q = 0; q < 4; ++q) {
                yv[q*4+0] = b4[q].x; yv[q*4+1] = b4[q].y;
                yv[q*4+2] = b4[q].z; yv[q*4+3] = b4[q].w;
            }
            #pragma unroll
            for (int c = 0; c < 16; ++c) {
                float s = yv[c];
                #pragma unroll
                for (int k = 0; k < 8; ++k)
                    s = fmaf(a8[k], f2[c*8 + k], s);   // f2 lane-uniform -> s_load
                yv[c] = s;
            }
            float4* o = (float4*)(y + (size_t)(n0 + row) * 4096 + tt * 16);
            #pragma unroll
            for (int q = 0; q < 4; ++q)
                o[q] = make_float4(yv[q*4+0], yv[q*4+1], yv[q*4+2], yv[q*4+3]);
        }
        lds_barrier();   // WAR: protect w1s before next iteration's writes
    }
}

// ---------------------------------------------------------------------------
extern "C" void kernel_launch(void* const* d_in, const int* in_sizes, int n_in,
                              void* d_out, int out_size, void* d_ws, size_t ws_size,
                              hipStream_t stream)
{
    const float* x    = (const float*)d_in[0];
    const float* core = (const float*)d_in[1];
    const float* f0   = (const float*)d_in[2];
    const float* f1   = (const float*)d_in[3];
    const float* f2   = (const float*)d_in[4];
    const float* f3   = (const float*)d_in[5];
    const float* f4   = (const float*)d_in[6];
    const float* f5   = (const float*)d_in[7];
    const float* bias = (const float*)d_in[8];
    float* y = (float*)d_out;

    const int N = in_sizes[0] / 4096;

    // workspace: u3b bf16 [N,512] (4MB) | coreb bf16 [512,512] (0.5MB)
    unsigned short* u3b   = (unsigned short*)d_ws;
    unsigned short* coreb = u3b + (size_t)N * 512;

    k_in_contract<<<N, THREADS, 0, stream>>>(x, f3, f4, f5, u3b, N);
    k_convert_core<<<256, THREADS, 0, stream>>>(core, coreb);
    k_gemm_expand<<<N / 16, GE_THREADS, 0, stream>>>(u3b, coreb, f0, f1, f2,
                                                     bias, y, N);
}